// Round 18
// baseline (205.539 us; speedup 1.0000x reference)
//
#include <hip/hip_runtime.h>
#include <hip/hip_bf16.h>
#include <cstdint>

#define B_ 2
#define S_ 2048
#define E_ 2048
#define H_ 32
#define KVH_ 8
#define D_ 64

typedef __bf16 bf16;
typedef __bf16 bf16x4 __attribute__((ext_vector_type(4)));
typedef __bf16 bf16x8 __attribute__((ext_vector_type(8)));
typedef float f32x4 __attribute__((ext_vector_type(4)));

// ---------------- fused prologue: cast x, transpose+cast 4 weights, rope table ----------------
__global__ __launch_bounds__(256) void prologue_k(const float* __restrict__ x,
                                                  const float* __restrict__ Wq,
                                                  const float* __restrict__ Wk,
                                                  const float* __restrict__ Wv,
                                                  const float* __restrict__ Wo,
                                                  bf16* __restrict__ xb,
                                                  bf16* __restrict__ WqkvT,
                                                  bf16* __restrict__ WoT,
                                                  float* __restrict__ tbl) {
    const int bx = blockIdx.x;
    const int tid = threadIdx.x;
    if (bx < 8192) {
        int i = (bx * 256 + tid) * 4;
        f32x4 v = *(const f32x4*)(x + i);
        bf16x4 o;
        o[0] = (bf16)v[0]; o[1] = (bf16)v[1]; o[2] = (bf16)v[2]; o[3] = (bf16)v[3];
        *(bf16x4*)(xb + i) = o;
    } else if (bx < 24576) {
        __shared__ float tile[32][33];
        const int i = bx - 8192;
        const int z = i >> 12, rem = i & 4095;
        const int bxx = rem & 63, byy = rem >> 6;
        const float* src;
        bf16* dst;
        int C;
        if (z == 0)      { src = Wq; dst = WqkvT;                       C = 2048; }
        else if (z == 1) { src = Wk; dst = WqkvT + (size_t)2048 * 2048; C = 512;  }
        else if (z == 2) { src = Wv; dst = WqkvT + (size_t)2560 * 2048; C = 512;  }
        else             { src = Wo; dst = WoT;                         C = 2048; }
        int c0 = bxx * 32, r0 = byy * 32;
        if (c0 >= C) return;
        int tx = tid & 31, ty = tid >> 5;  // (32, 8)
#pragma unroll
        for (int k = 0; k < 4; k++)
            tile[ty + 8 * k][tx] = src[(size_t)(r0 + ty + 8 * k) * C + c0 + tx];
        __syncthreads();
#pragma unroll
        for (int k = 0; k < 4; k++)
            dst[(size_t)(c0 + ty + 8 * k) * 2048 + r0 + tx] = (bf16)tile[tx][ty + 8 * k];
    } else {
        int t = (bx - 24576) * 256 + tid;  // S_*32 threads
        int dp = t & 31, s = t >> 5;
        float invf = exp2f(-(float)dp * (13.287712379549449f / 32.0f));  // 10000^(-dp/32)
        float ang = (float)s * invf;
        tbl[t * 2] = cosf(ang);
        tbl[t * 2 + 1] = sinf(ang);
    }
}

// ---------------- async global->LDS 16B helper (m97 pattern) ----------------
__device__ __forceinline__ void gload16(const bf16* g, bf16* l) {
    __builtin_amdgcn_global_load_lds((const __attribute__((address_space(1))) uint32_t*)g,
                                     (__attribute__((address_space(3))) uint32_t*)l, 16, 0, 0);
}

// ---------------- bf16 MFMA GEMM: C[M][N] = A[M][2048] * Bt[N][2048]^T ----------------
// BK=64, global_load_lds staging, linear LDS [128][64] with T2 both-sides XOR swizzle,
// 2-barrier loop, XCD swizzle. MODE 0: fused RoPE; scatter Q/K, V transposed. MODE 1: f32 out.
template <int MODE>
__global__ __launch_bounds__(256, 3) void gemm_bf16_k(const bf16* __restrict__ A,
                                                      const bf16* __restrict__ Bt,
                                                      bf16* __restrict__ Q, bf16* __restrict__ Kb,
                                                      bf16* __restrict__ Vb, float* __restrict__ Cf,
                                                      const float* __restrict__ tbl) {
    __shared__ bf16 As[128 * 64];
    __shared__ bf16 Bs[128 * 64];
    const int t = threadIdx.x;
    const int lane = t & 63, w = t >> 6;
    const int wm = w >> 1, wn = w & 1;
    const int g = lane >> 4, l15 = lane & 15;
    // XCD-aware swizzle (nwg % 8 == 0 for both call sites)
    const int flat = blockIdx.x + gridDim.x * blockIdx.y;
    const int cpx = (gridDim.x * gridDim.y) >> 3;
    const int swz = (flat & 7) * cpx + (flat >> 3);
    const int m0 = (swz / gridDim.x) * 128, n0 = (swz % gridDim.x) * 128;

    f32x4 acc[4][4];
#pragma unroll
    for (int i = 0; i < 4; i++)
#pragma unroll
        for (int j = 0; j < 4; j++) acc[i][j] = f32x4{0.f, 0.f, 0.f, 0.f};

    // staging: wave w covers rows w*32 + i*8 + (lane>>3), source col pre-inverse-swizzled
    const int lrow = lane >> 3;                    // 0..7
    const int lcol = ((lane & 7) ^ lrow) * 8;      // involution within the 64-elem row
    const bf16* ga = A + (size_t)(m0 + w * 32 + lrow) * 2048 + lcol;
    const bf16* gb = Bt + (size_t)(n0 + w * 32 + lrow) * 2048 + lcol;
    bf16* la = As + w * 2048;  // wave-uniform LDS dest; HW adds lane*16B
    bf16* lb = Bs + w * 2048;

    const int rxor = (l15 & 7) * 8;  // read-side XOR (elems)

    for (int k0 = 0; k0 < 2048; k0 += 64) {
        __syncthreads();  // everyone done reading LDS of prev step
#pragma unroll
        for (int i = 0; i < 4; i++) {
            gload16(ga + k0 + (size_t)i * 8 * 2048, la + i * 512);
            gload16(gb + k0 + (size_t)i * 8 * 2048, lb + i * 512);
        }
        __syncthreads();  // vmcnt(0) drain + visibility
        bf16x8 af[4][2], bfr[4][2];
#pragma unroll
        for (int i = 0; i < 4; i++)
#pragma unroll
            for (int ks = 0; ks < 2; ks++) {
                const int coff = (ks * 32 + g * 8) ^ rxor;
                af[i][ks] = *(const bf16x8*)(As + (wm * 64 + i * 16 + l15) * 64 + coff);
                bfr[i][ks] = *(const bf16x8*)(Bs + (wn * 64 + i * 16 + l15) * 64 + coff);
            }
#pragma unroll
        for (int ks = 0; ks < 2; ks++)
#pragma unroll
            for (int i = 0; i < 4; i++)
#pragma unroll
                for (int j = 0; j < 4; j++)
                    acc[i][j] = __builtin_amdgcn_mfma_f32_16x16x32_bf16(af[i][ks], bfr[j][ks],
                                                                        acc[i][j], 0, 0, 0);
    }

    const int nbase = n0 + wn * 64;  // 64-aligned => whole j-span is one head/region
#pragma unroll
    for (int i = 0; i < 4; i++) {
        int mB = m0 + wm * 64 + i * 16 + g * 4;
        int b = mB >> 11, s = mB & 2047;
        if constexpr (MODE == 0) {
            if (nbase < 2560) {
                // fused RoPE on columns: pairs (j, j+2) == dims (d, d+32), d = j*16+l15
#pragma unroll
                for (int jh = 0; jh < 2; jh++) {
                    int dp = jh * 16 + l15;
#pragma unroll
                    for (int r = 0; r < 4; r++) {
                        const float* cs = tbl + ((size_t)(s + r) * 32 + dp) * 2;
                        float cv = cs[0], sv = cs[1];
                        float lo = acc[i][jh][r], hi = acc[i][jh + 2][r];
                        acc[i][jh][r] = lo * cv - hi * sv;
                        acc[i][jh + 2][r] = lo * sv + hi * cv;
                    }
                }
            }
        }
#pragma unroll
        for (int j = 0; j < 4; j++) {
            int n = nbase + j * 16 + l15;
            f32x4 v = acc[i][j];
            if constexpr (MODE == 0) {
                if (n < 2048) {
                    bf16* dst = Q + (((size_t)b * H_ + (n >> 6)) * S_ + s) * D_ + (n & 63);
#pragma unroll
                    for (int r = 0; r < 4; r++) dst[r * 64] = (bf16)v[r];
                } else if (n < 2560) {
                    bf16* dst = Kb + (((size_t)b * KVH_ + ((n - 2048) >> 6)) * S_ + s) * D_ + (n & 63);
#pragma unroll
                    for (int r = 0; r < 4; r++) dst[r * 64] = (bf16)v[r];
                } else {
                    // V transposed: [b][kvh][d=64][s=2048]
                    int vh = (n - 2560) >> 6, d = n & 63;
                    bf16* dst = Vb + (((size_t)b * KVH_ + vh) * 64 + d) * 2048 + s;
                    bf16x4 o;
#pragma unroll
                    for (int r = 0; r < 4; r++) o[r] = (bf16)v[r];
                    *(bf16x4*)dst = o;
                }
            } else {
#pragma unroll
                for (int r = 0; r < 4; r++) Cf[(size_t)(mB + r) * 2048 + n] = v[r];
            }
        }
    }
}

// ---------------- MFMA flash attention v14: complementary 16-row pairing (uniform compute) ----
// Base = round-17 green v12; ONLY the qrow/ns formulas change. Block y (grid (KVH,64,B)
// unchanged): waves u=0 own 16-row chunk y (rows 16y..), u=1 own chunk 127-y (rows
// 16(127-y)..). Per-block COMPUTE is uniform (~32 units +-1) by construction, independent
// of block->CU placement (v12's per-block work spanned 1..17 stages -> ~30% tail stall).
// Staging runs to the hi chunk's range: ns = ((127-y)*16+15)/128 + 1 (9..16, milder spread).
// Coverage bijective: lo chunks cover rows 0..1023, hi 1024..2047. Everything else
// byte-identical to green: XCD affinity, reg-staged K/V + prefetch, no-max softmax,
// l via ones-MFMA, wave-uniform continue for the lo chunk's early exit.
__global__ __launch_bounds__(512, 4) void attn_mfma14_k(const bf16* __restrict__ Q,
                                                        const bf16* __restrict__ Kb,
                                                        const bf16* __restrict__ Vtg,
                                                        bf16* __restrict__ Out) {
    __shared__ bf16 Ks[128 * 72];
    __shared__ bf16 Vts[64 * 136];
    const int t = threadIdx.x;
    const int w = t >> 6, lane = t & 63, g = lane >> 4, l15 = lane & 15;
    const int hh = w >> 1, u = w & 1;
    const int kvh = blockIdx.x, b = blockIdx.z;
    const int y = blockIdx.y;
    const int h = kvh * 4 + hh;
    const int qrow = (u == 0) ? (y * 16) : ((127 - y) * 16);  // complementary pair
    const int ns = (((127 - y) * 16 + 15) >> 7) + 1;          // stages to cover hi chunk

    const bf16* qbase = Q + ((size_t)b * H_ + h) * (size_t)(S_ * D_);
    const bf16* kbase = Kb + ((size_t)b * KVH_ + kvh) * (size_t)(S_ * D_);
    const bf16* vtbase = Vtg + ((size_t)b * KVH_ + kvh) * (size_t)(S_ * D_);

    const float SC = 0.18033688011112042f;  // log2(e)/8, folded into Q frags

    // Q fragments (B-operand layout, q = col = l15), pre-scaled by SC
    bf16x8 qf[2];  // [ks]
#pragma unroll
    for (int ks = 0; ks < 2; ks++) {
        bf16x8 raw = *(const bf16x8*)(qbase + (size_t)(qrow + l15) * 64 + ks * 32 + g * 8);
        bf16x8 sc8;
#pragma unroll
        for (int e = 0; e < 8; e++) sc8[e] = (bf16)((float)raw[e] * SC);
        qf[ks] = sc8;
    }

    // constant all-ones A-frag for the l-accumulating MFMA
    bf16x8 ones1;
#pragma unroll
    for (int e = 0; e < 8; e++) ones1[e] = (bf16)1.0f;

    f32x4 accO[4];  // [df]: O^T rows d=df*16+g*4+r, col q=l15
    f32x4 accL;     // every element = l(q=l15) after all tiles
#pragma unroll
    for (int df = 0; df < 4; df++) accO[df] = f32x4{0.f, 0.f, 0.f, 0.f};
    accL = f32x4{0.f, 0.f, 0.f, 0.f};

    const int krow = t >> 3;          // 0..63
    const int kch = (t & 7) * 8;

    bf16x8 kA, kB, vA, vB;
#define LOADT(J0)                                                               \
    kA = *(const bf16x8*)(kbase + (size_t)((J0) + krow) * 64 + kch);            \
    kB = *(const bf16x8*)(kbase + (size_t)((J0) + 64 + krow) * 64 + kch);       \
    vA = *(const bf16x8*)(vtbase + (size_t)krow * 2048 + (J0) + kch);           \
    vB = *(const bf16x8*)(vtbase + (size_t)krow * 2048 + (J0) + 64 + kch);

    LOADT(0)
    for (int si = 0; si < ns; si++) {
        const int J = si * 128;
        __syncthreads();  // all waves done reading LDS (prev stage)
        *(bf16x8*)(Ks + krow * 72 + kch) = kA;
        *(bf16x8*)(Ks + (krow + 64) * 72 + kch) = kB;
        *(bf16x8*)(Vts + krow * 136 + kch) = vA;
        *(bf16x8*)(Vts + krow * 136 + 64 + kch) = vB;
        __syncthreads();  // staged data visible
        if (si + 1 < ns) { LOADT(J + 128) }  // prefetch next stage under compute

#pragma unroll
        for (int sub = 0; sub < 2; sub++) {
            const int j0 = J + sub * 64;
            if (j0 > qrow + 15) continue;  // beyond this wave's rows (wave-uniform)

            // --- K frags for this sub-tile
            bf16x8 kf[4][2];
#pragma unroll
            for (int nf = 0; nf < 4; nf++)
#pragma unroll
                for (int ks = 0; ks < 2; ks++)
                    kf[nf][ks] = *(const bf16x8*)(Ks + (sub * 64 + nf * 16 + l15) * 72 +
                                                  ks * 32 + g * 8);

            f32x4 st[4];
            __builtin_amdgcn_s_setprio(1);
#pragma unroll
            for (int nf = 0; nf < 4; nf++) {
                st[nf] = f32x4{0.f, 0.f, 0.f, 0.f};
#pragma unroll
                for (int ks = 0; ks < 2; ks++)
                    st[nf] = __builtin_amdgcn_mfma_f32_16x16x32_bf16(kf[nf][ks], qf[ks],
                                                                     st[nf], 0, 0, 0);
            }
            __builtin_amdgcn_s_setprio(0);
            const int q = qrow + l15;
            float sv[4][4];
            if (j0 + 63 > qrow) {  // diagonal tile: mask
#pragma unroll
                for (int nf = 0; nf < 4; nf++)
#pragma unroll
                    for (int r = 0; r < 4; r++)
                        sv[nf][r] = (j0 + nf * 16 + g * 4 + r > q) ? -1e30f : st[nf][r];
            } else {
#pragma unroll
                for (int nf = 0; nf < 4; nf++)
#pragma unroll
                    for (int r = 0; r < 4; r++) sv[nf][r] = st[nf][r];
            }
            // no-max softmax: p = exp2(s); normalization absorbed by 1/l (exact)
#pragma unroll
            for (int nf = 0; nf < 4; nf++)
#pragma unroll
                for (int r = 0; r < 4; r++) sv[nf][r] = exp2f(sv[nf][r]);
            // pack P to bf16 B-frags: e=nfp*4+r  <->  kv=kslot*32+nfp*16+g*4+r
            bf16x8 pb[2];
#pragma unroll
            for (int kslot = 0; kslot < 2; kslot++)
#pragma unroll
                for (int nfp = 0; nfp < 2; nfp++)
#pragma unroll
                    for (int r = 0; r < 4; r++)
                        pb[kslot][nfp * 4 + r] = (bf16)sv[kslot * 2 + nfp][r];

            // --- PV: O^T += V^T_frag * P_frag; l += ones * P_frag (perm-invariant sum)
            __builtin_amdgcn_s_setprio(1);
#pragma unroll
            for (int kslot = 0; kslot < 2; kslot++)
                accL = __builtin_amdgcn_mfma_f32_16x16x32_bf16(ones1, pb[kslot], accL, 0, 0, 0);
#pragma unroll
            for (int df = 0; df < 4; df++) {
                const bf16* vrow = Vts + (df * 16 + l15) * 136 + sub * 64;
#pragma unroll
                for (int kslot = 0; kslot < 2; kslot++) {
                    bf16x4 lo = *(const bf16x4*)(vrow + kslot * 32 + g * 4);
                    bf16x4 hi = *(const bf16x4*)(vrow + kslot * 32 + 16 + g * 4);
                    bf16x8 va = __builtin_shufflevector(lo, hi, 0, 1, 2, 3, 4, 5, 6, 7);
                    accO[df] = __builtin_amdgcn_mfma_f32_16x16x32_bf16(va, pb[kslot],
                                                                      accO[df], 0, 0, 0);
                }
            }
            __builtin_amdgcn_s_setprio(0);
        }
    }
#undef LOADT

    // --- epilogue: lane holds O^T[d=df*16+g*4+r][q=qrow+l15]; l in accL[0]
    {
        const float inv = 1.f / accL[0];
        const int s = qrow + l15;
        bf16* obase = Out + ((size_t)(b * S_ + s)) * 2048 + h * 64 + g * 4;
#pragma unroll
        for (int df = 0; df < 4; df++) {
            bf16x4 o;
#pragma unroll
            for (int r = 0; r < 4; r++) o[r] = (bf16)(accO[df][r] * inv);
            *(bf16x4*)(obase + df * 16) = o;
        }
    }
}

extern "C" void kernel_launch(void* const* d_in, const int* in_sizes, int n_in,
                              void* d_out, int out_size, void* d_ws, size_t ws_size,
                              hipStream_t stream) {
    const float* x = (const float*)d_in[0];
    const float* Wq = (const float*)d_in[1];
    const float* Wk = (const float*)d_in[2];
    const float* Wv = (const float*)d_in[3];
    const float* Wo = (const float*)d_in[4];
    float* out = (float*)d_out;

    char* ws = (char*)d_ws;
    size_t off = 0;
    auto alloc = [&](size_t bytes) {
        void* p = ws + off;
        off += (bytes + 255) & ~(size_t)255;
        return p;
    };
    bf16* xb = (bf16*)alloc((size_t)4096 * 2048 * 2);
    bf16* WqkvT = (bf16*)alloc((size_t)3072 * 2048 * 2);
    bf16* WoT = (bf16*)alloc((size_t)2048 * 2048 * 2);
    bf16* Qb = (bf16*)alloc((size_t)B_ * H_ * S_ * D_ * 2);
    bf16* Kb = (bf16*)alloc((size_t)B_ * KVH_ * S_ * D_ * 2);
    bf16* Vb = (bf16*)alloc((size_t)B_ * KVH_ * S_ * D_ * 2);  // transposed [b][kvh][d][s]
    float* tbl = (float*)alloc((size_t)S_ * 32 * 2 * sizeof(float));
    bf16* attn = xb;  // alias: xb dead after QKV GEMM

    prologue_k<<<24832, 256, 0, stream>>>(x, Wq, Wk, Wv, Wo, xb, WqkvT, WoT, tbl);

    // QKV GEMM with fused RoPE (needs tbl)
    gemm_bf16_k<0><<<dim3(24, 32), 256, 0, stream>>>(xb, WqkvT, Qb, Kb, Vb, nullptr, tbl);

    attn_mfma14_k<<<dim3(KVH_, 64, B_), 512, 0, stream>>>(Qb, Kb, Vb, attn);

    gemm_bf16_k<1><<<dim3(16, 32), 256, 0, stream>>>(attn, WoT, nullptr, nullptr, nullptr, out, nullptr);
}

// Round 19
// 184.667 us; speedup vs baseline: 1.1130x; 1.1130x over previous
//
#include <hip/hip_runtime.h>
#include <hip/hip_bf16.h>
#include <cstdint>

#define B_ 2
#define S_ 2048
#define E_ 2048
#define H_ 32
#define KVH_ 8
#define D_ 64

typedef __bf16 bf16;
typedef __bf16 bf16x4 __attribute__((ext_vector_type(4)));
typedef __bf16 bf16x8 __attribute__((ext_vector_type(8)));
typedef float f32x4 __attribute__((ext_vector_type(4)));

// ---------------- fused prologue: cast x, transpose+cast 4 weights, rope table ----------------
__global__ __launch_bounds__(256) void prologue_k(const float* __restrict__ x,
                                                  const float* __restrict__ Wq,
                                                  const float* __restrict__ Wk,
                                                  const float* __restrict__ Wv,
                                                  const float* __restrict__ Wo,
                                                  bf16* __restrict__ xb,
                                                  bf16* __restrict__ WqkvT,
                                                  bf16* __restrict__ WoT,
                                                  float* __restrict__ tbl) {
    const int bx = blockIdx.x;
    const int tid = threadIdx.x;
    if (bx < 8192) {
        int i = (bx * 256 + tid) * 4;
        f32x4 v = *(const f32x4*)(x + i);
        bf16x4 o;
        o[0] = (bf16)v[0]; o[1] = (bf16)v[1]; o[2] = (bf16)v[2]; o[3] = (bf16)v[3];
        *(bf16x4*)(xb + i) = o;
    } else if (bx < 24576) {
        __shared__ float tile[32][33];
        const int i = bx - 8192;
        const int z = i >> 12, rem = i & 4095;
        const int bxx = rem & 63, byy = rem >> 6;
        const float* src;
        bf16* dst;
        int C;
        if (z == 0)      { src = Wq; dst = WqkvT;                       C = 2048; }
        else if (z == 1) { src = Wk; dst = WqkvT + (size_t)2048 * 2048; C = 512;  }
        else if (z == 2) { src = Wv; dst = WqkvT + (size_t)2560 * 2048; C = 512;  }
        else             { src = Wo; dst = WoT;                         C = 2048; }
        int c0 = bxx * 32, r0 = byy * 32;
        if (c0 >= C) return;
        int tx = tid & 31, ty = tid >> 5;  // (32, 8)
#pragma unroll
        for (int k = 0; k < 4; k++)
            tile[ty + 8 * k][tx] = src[(size_t)(r0 + ty + 8 * k) * C + c0 + tx];
        __syncthreads();
#pragma unroll
        for (int k = 0; k < 4; k++)
            dst[(size_t)(c0 + ty + 8 * k) * 2048 + r0 + tx] = (bf16)tile[tx][ty + 8 * k];
    } else {
        int t = (bx - 24576) * 256 + tid;  // S_*32 threads
        int dp = t & 31, s = t >> 5;
        float invf = exp2f(-(float)dp * (13.287712379549449f / 32.0f));  // 10000^(-dp/32)
        float ang = (float)s * invf;
        tbl[t * 2] = cosf(ang);
        tbl[t * 2 + 1] = sinf(ang);
    }
}

// ---------------- async global->LDS 16B helper (m97 pattern) ----------------
__device__ __forceinline__ void gload16(const bf16* g, bf16* l) {
    __builtin_amdgcn_global_load_lds((const __attribute__((address_space(1))) uint32_t*)g,
                                     (__attribute__((address_space(3))) uint32_t*)l, 16, 0, 0);
}

// ---------------- bf16 MFMA GEMM: C[M][N] = A[M][2048] * Bt[N][2048]^T ----------------
// BK=64, global_load_lds staging, linear LDS [128][64] with T2 both-sides XOR swizzle,
// 2-barrier loop, XCD swizzle. MODE 0: fused RoPE; scatter Q/K, V transposed. MODE 1: f32 out.
template <int MODE>
__global__ __launch_bounds__(256, 3) void gemm_bf16_k(const bf16* __restrict__ A,
                                                      const bf16* __restrict__ Bt,
                                                      bf16* __restrict__ Q, bf16* __restrict__ Kb,
                                                      bf16* __restrict__ Vb, float* __restrict__ Cf,
                                                      const float* __restrict__ tbl) {
    __shared__ bf16 As[128 * 64];
    __shared__ bf16 Bs[128 * 64];
    const int t = threadIdx.x;
    const int lane = t & 63, w = t >> 6;
    const int wm = w >> 1, wn = w & 1;
    const int g = lane >> 4, l15 = lane & 15;
    // XCD-aware swizzle (nwg % 8 == 0 for both call sites)
    const int flat = blockIdx.x + gridDim.x * blockIdx.y;
    const int cpx = (gridDim.x * gridDim.y) >> 3;
    const int swz = (flat & 7) * cpx + (flat >> 3);
    const int m0 = (swz / gridDim.x) * 128, n0 = (swz % gridDim.x) * 128;

    f32x4 acc[4][4];
#pragma unroll
    for (int i = 0; i < 4; i++)
#pragma unroll
        for (int j = 0; j < 4; j++) acc[i][j] = f32x4{0.f, 0.f, 0.f, 0.f};

    // staging: wave w covers rows w*32 + i*8 + (lane>>3), source col pre-inverse-swizzled
    const int lrow = lane >> 3;                    // 0..7
    const int lcol = ((lane & 7) ^ lrow) * 8;      // involution within the 64-elem row
    const bf16* ga = A + (size_t)(m0 + w * 32 + lrow) * 2048 + lcol;
    const bf16* gb = Bt + (size_t)(n0 + w * 32 + lrow) * 2048 + lcol;
    bf16* la = As + w * 2048;  // wave-uniform LDS dest; HW adds lane*16B
    bf16* lb = Bs + w * 2048;

    const int rxor = (l15 & 7) * 8;  // read-side XOR (elems)

    for (int k0 = 0; k0 < 2048; k0 += 64) {
        __syncthreads();  // everyone done reading LDS of prev step
#pragma unroll
        for (int i = 0; i < 4; i++) {
            gload16(ga + k0 + (size_t)i * 8 * 2048, la + i * 512);
            gload16(gb + k0 + (size_t)i * 8 * 2048, lb + i * 512);
        }
        __syncthreads();  // vmcnt(0) drain + visibility
        bf16x8 af[4][2], bfr[4][2];
#pragma unroll
        for (int i = 0; i < 4; i++)
#pragma unroll
            for (int ks = 0; ks < 2; ks++) {
                const int coff = (ks * 32 + g * 8) ^ rxor;
                af[i][ks] = *(const bf16x8*)(As + (wm * 64 + i * 16 + l15) * 64 + coff);
                bfr[i][ks] = *(const bf16x8*)(Bs + (wn * 64 + i * 16 + l15) * 64 + coff);
            }
#pragma unroll
        for (int ks = 0; ks < 2; ks++)
#pragma unroll
            for (int i = 0; i < 4; i++)
#pragma unroll
                for (int j = 0; j < 4; j++)
                    acc[i][j] = __builtin_amdgcn_mfma_f32_16x16x32_bf16(af[i][ks], bfr[j][ks],
                                                                        acc[i][j], 0, 0, 0);
    }

    const int nbase = n0 + wn * 64;  // 64-aligned => whole j-span is one head/region
#pragma unroll
    for (int i = 0; i < 4; i++) {
        int mB = m0 + wm * 64 + i * 16 + g * 4;
        int b = mB >> 11, s = mB & 2047;
        if constexpr (MODE == 0) {
            if (nbase < 2560) {
                // fused RoPE on columns: pairs (j, j+2) == dims (d, d+32), d = j*16+l15
#pragma unroll
                for (int jh = 0; jh < 2; jh++) {
                    int dp = jh * 16 + l15;
#pragma unroll
                    for (int r = 0; r < 4; r++) {
                        const float* cs = tbl + ((size_t)(s + r) * 32 + dp) * 2;
                        float cv = cs[0], sv = cs[1];
                        float lo = acc[i][jh][r], hi = acc[i][jh + 2][r];
                        acc[i][jh][r] = lo * cv - hi * sv;
                        acc[i][jh + 2][r] = lo * sv + hi * cv;
                    }
                }
            }
        }
#pragma unroll
        for (int j = 0; j < 4; j++) {
            int n = nbase + j * 16 + l15;
            f32x4 v = acc[i][j];
            if constexpr (MODE == 0) {
                if (n < 2048) {
                    bf16* dst = Q + (((size_t)b * H_ + (n >> 6)) * S_ + s) * D_ + (n & 63);
#pragma unroll
                    for (int r = 0; r < 4; r++) dst[r * 64] = (bf16)v[r];
                } else if (n < 2560) {
                    bf16* dst = Kb + (((size_t)b * KVH_ + ((n - 2048) >> 6)) * S_ + s) * D_ + (n & 63);
#pragma unroll
                    for (int r = 0; r < 4; r++) dst[r * 64] = (bf16)v[r];
                } else {
                    // V transposed: [b][kvh][d=64][s=2048]
                    int vh = (n - 2560) >> 6, d = n & 63;
                    bf16* dst = Vb + (((size_t)b * KVH_ + vh) * 64 + d) * 2048 + s;
                    bf16x4 o;
#pragma unroll
                    for (int r = 0; r < 4; r++) o[r] = (bf16)v[r];
                    *(bf16x4*)dst = o;
                }
            } else {
#pragma unroll
                for (int r = 0; r < 4; r++) Cf[(size_t)(mB + r) * 2048 + n] = v[r];
            }
        }
    }
}

// ---------------- MFMA flash attention v12 (best green): one 32-row chunk/block ----------------
// Grid dim3(KVH, 64, B) = 1024 blocks = 4/CU (wave-limit max), c = 63 - blockIdx.y — the best
// MEASURED mapping (serpentine and complementary-pairing variants both regressed; staging
// volume dominates and placement is opaque). XCD affinity flat%8=kvh; reg-staged K/V +
// prefetch; no-max softmax (p=exp2(s)); l via ones-MFMA. LDS: K [128][72], V^T [64][136].
__global__ __launch_bounds__(512, 4) void attn_mfma12_k(const bf16* __restrict__ Q,
                                                        const bf16* __restrict__ Kb,
                                                        const bf16* __restrict__ Vtg,
                                                        bf16* __restrict__ Out) {
    __shared__ bf16 Ks[128 * 72];
    __shared__ bf16 Vts[64 * 136];
    const int t = threadIdx.x;
    const int w = t >> 6, lane = t & 63, g = lane >> 4, l15 = lane & 15;
    const int hh = w >> 1, u = w & 1;
    const int kvh = blockIdx.x, b = blockIdx.z;
    const int c = 63 - blockIdx.y;  // big (17-stage) blocks first
    const int h = kvh * 4 + hh;
    const int qrow = c * 32 + u * 16;
    const int ns = ((c * 32 + 31) >> 7) + 1;  // 128-kv stages (block-uniform)

    const bf16* qbase = Q + ((size_t)b * H_ + h) * (size_t)(S_ * D_);
    const bf16* kbase = Kb + ((size_t)b * KVH_ + kvh) * (size_t)(S_ * D_);
    const bf16* vtbase = Vtg + ((size_t)b * KVH_ + kvh) * (size_t)(S_ * D_);

    const float SC = 0.18033688011112042f;  // log2(e)/8, folded into Q frags

    // Q fragments (B-operand layout, q = col = l15), pre-scaled by SC
    bf16x8 qf[2];  // [ks]
#pragma unroll
    for (int ks = 0; ks < 2; ks++) {
        bf16x8 raw = *(const bf16x8*)(qbase + (size_t)(qrow + l15) * 64 + ks * 32 + g * 8);
        bf16x8 sc8;
#pragma unroll
        for (int e = 0; e < 8; e++) sc8[e] = (bf16)((float)raw[e] * SC);
        qf[ks] = sc8;
    }

    // constant all-ones A-frag for the l-accumulating MFMA
    bf16x8 ones1;
#pragma unroll
    for (int e = 0; e < 8; e++) ones1[e] = (bf16)1.0f;

    f32x4 accO[4];  // [df]: O^T rows d=df*16+g*4+r, col q=l15
    f32x4 accL;     // every element = l(q=l15) after all tiles
#pragma unroll
    for (int df = 0; df < 4; df++) accO[df] = f32x4{0.f, 0.f, 0.f, 0.f};
    accL = f32x4{0.f, 0.f, 0.f, 0.f};

    const int krow = t >> 3;          // 0..63
    const int kch = (t & 7) * 8;

    bf16x8 kA, kB, vA, vB;
#define LOADT(J0)                                                               \
    kA = *(const bf16x8*)(kbase + (size_t)((J0) + krow) * 64 + kch);            \
    kB = *(const bf16x8*)(kbase + (size_t)((J0) + 64 + krow) * 64 + kch);       \
    vA = *(const bf16x8*)(vtbase + (size_t)krow * 2048 + (J0) + kch);           \
    vB = *(const bf16x8*)(vtbase + (size_t)krow * 2048 + (J0) + 64 + kch);

    LOADT(0)
    for (int si = 0; si < ns; si++) {
        const int J = si * 128;
        __syncthreads();  // all waves done reading LDS (prev stage)
        *(bf16x8*)(Ks + krow * 72 + kch) = kA;
        *(bf16x8*)(Ks + (krow + 64) * 72 + kch) = kB;
        *(bf16x8*)(Vts + krow * 136 + kch) = vA;
        *(bf16x8*)(Vts + krow * 136 + 64 + kch) = vB;
        __syncthreads();  // staged data visible
        if (si + 1 < ns) { LOADT(J + 128) }  // prefetch next stage under compute

#pragma unroll
        for (int sub = 0; sub < 2; sub++) {
            const int j0 = J + sub * 64;
            if (j0 > qrow + 15) continue;  // beyond this wave's rows (wave-uniform)

            // --- K frags for this sub-tile
            bf16x8 kf[4][2];
#pragma unroll
            for (int nf = 0; nf < 4; nf++)
#pragma unroll
                for (int ks = 0; ks < 2; ks++)
                    kf[nf][ks] = *(const bf16x8*)(Ks + (sub * 64 + nf * 16 + l15) * 72 +
                                                  ks * 32 + g * 8);

            f32x4 st[4];
            __builtin_amdgcn_s_setprio(1);
#pragma unroll
            for (int nf = 0; nf < 4; nf++) {
                st[nf] = f32x4{0.f, 0.f, 0.f, 0.f};
#pragma unroll
                for (int ks = 0; ks < 2; ks++)
                    st[nf] = __builtin_amdgcn_mfma_f32_16x16x32_bf16(kf[nf][ks], qf[ks],
                                                                     st[nf], 0, 0, 0);
            }
            __builtin_amdgcn_s_setprio(0);
            const int q = qrow + l15;
            float sv[4][4];
            if (j0 + 63 > qrow) {  // diagonal tile: mask
#pragma unroll
                for (int nf = 0; nf < 4; nf++)
#pragma unroll
                    for (int r = 0; r < 4; r++)
                        sv[nf][r] = (j0 + nf * 16 + g * 4 + r > q) ? -1e30f : st[nf][r];
            } else {
#pragma unroll
                for (int nf = 0; nf < 4; nf++)
#pragma unroll
                    for (int r = 0; r < 4; r++) sv[nf][r] = st[nf][r];
            }
            // no-max softmax: p = exp2(s); normalization absorbed by 1/l (exact)
#pragma unroll
            for (int nf = 0; nf < 4; nf++)
#pragma unroll
                for (int r = 0; r < 4; r++) sv[nf][r] = exp2f(sv[nf][r]);
            // pack P to bf16 B-frags: e=nfp*4+r  <->  kv=kslot*32+nfp*16+g*4+r
            bf16x8 pb[2];
#pragma unroll
            for (int kslot = 0; kslot < 2; kslot++)
#pragma unroll
                for (int nfp = 0; nfp < 2; nfp++)
#pragma unroll
                    for (int r = 0; r < 4; r++)
                        pb[kslot][nfp * 4 + r] = (bf16)sv[kslot * 2 + nfp][r];

            // --- PV: O^T += V^T_frag * P_frag; l += ones * P_frag (perm-invariant sum)
            __builtin_amdgcn_s_setprio(1);
#pragma unroll
            for (int kslot = 0; kslot < 2; kslot++)
                accL = __builtin_amdgcn_mfma_f32_16x16x32_bf16(ones1, pb[kslot], accL, 0, 0, 0);
#pragma unroll
            for (int df = 0; df < 4; df++) {
                const bf16* vrow = Vts + (df * 16 + l15) * 136 + sub * 64;
#pragma unroll
                for (int kslot = 0; kslot < 2; kslot++) {
                    bf16x4 lo = *(const bf16x4*)(vrow + kslot * 32 + g * 4);
                    bf16x4 hi = *(const bf16x4*)(vrow + kslot * 32 + 16 + g * 4);
                    bf16x8 va = __builtin_shufflevector(lo, hi, 0, 1, 2, 3, 4, 5, 6, 7);
                    accO[df] = __builtin_amdgcn_mfma_f32_16x16x32_bf16(va, pb[kslot],
                                                                      accO[df], 0, 0, 0);
                }
            }
            __builtin_amdgcn_s_setprio(0);
        }
    }
#undef LOADT

    // --- epilogue: lane holds O^T[d=df*16+g*4+r][q=qrow+l15]; l in accL[0]
    {
        const float inv = 1.f / accL[0];
        const int s = qrow + l15;
        bf16* obase = Out + ((size_t)(b * S_ + s)) * 2048 + h * 64 + g * 4;
#pragma unroll
        for (int df = 0; df < 4; df++) {
            bf16x4 o;
#pragma unroll
            for (int r = 0; r < 4; r++) o[r] = (bf16)(accO[df][r] * inv);
            *(bf16x4*)(obase + df * 16) = o;
        }
    }
}

extern "C" void kernel_launch(void* const* d_in, const int* in_sizes, int n_in,
                              void* d_out, int out_size, void* d_ws, size_t ws_size,
                              hipStream_t stream) {
    const float* x = (const float*)d_in[0];
    const float* Wq = (const float*)d_in[1];
    const float* Wk = (const float*)d_in[2];
    const float* Wv = (const float*)d_in[3];
    const float* Wo = (const float*)d_in[4];
    float* out = (float*)d_out;

    char* ws = (char*)d_ws;
    size_t off = 0;
    auto alloc = [&](size_t bytes) {
        void* p = ws + off;
        off += (bytes + 255) & ~(size_t)255;
        return p;
    };
    bf16* xb = (bf16*)alloc((size_t)4096 * 2048 * 2);
    bf16* WqkvT = (bf16*)alloc((size_t)3072 * 2048 * 2);
    bf16* WoT = (bf16*)alloc((size_t)2048 * 2048 * 2);
    bf16* Qb = (bf16*)alloc((size_t)B_ * H_ * S_ * D_ * 2);
    bf16* Kb = (bf16*)alloc((size_t)B_ * KVH_ * S_ * D_ * 2);
    bf16* Vb = (bf16*)alloc((size_t)B_ * KVH_ * S_ * D_ * 2);  // transposed [b][kvh][d][s]
    float* tbl = (float*)alloc((size_t)S_ * 32 * 2 * sizeof(float));
    bf16* attn = xb;  // alias: xb dead after QKV GEMM

    prologue_k<<<24832, 256, 0, stream>>>(x, Wq, Wk, Wv, Wo, xb, WqkvT, WoT, tbl);

    // QKV GEMM with fused RoPE (needs tbl)
    gemm_bf16_k<0><<<dim3(24, 32), 256, 0, stream>>>(xb, WqkvT, Qb, Kb, Vb, nullptr, tbl);

    attn_mfma12_k<<<dim3(KVH_, 64, B_), 512, 0, stream>>>(Qb, Kb, Vb, attn);

    gemm_bf16_k<1><<<dim3(16, 32), 256, 0, stream>>>(attn, WoT, nullptr, nullptr, nullptr, out, nullptr);
}